// Round 1
// baseline (638.635 us; speedup 1.0000x reference)
//
#include <hip/hip_runtime.h>

// ---------------------------------------------------------------------------
// BoringAttention (talking-heads) on MI355X.
// Pipeline:
//   conv_bf16   : x fp32 -> xb bf16
//   transW x2   : Wq|Wkv -> WbT [3072][1024] bf16
//   gemm_bt     : xb @ W -> qkv bf16 [4096][3072] (q|k|v)
//   fill_K      : K_ws [b][h][2064][64] bf16 (mem_k prepended)
//   fill_Vt     : Vt_ws [b][h][64][2064] bf16 (transposed, mem_v prepended)
//   memset      : O_ws (fp32), l_ws (fp32)
//   attn_stats  : i-tile 32, ONE barrier/round software pipeline:
//                 body(n) = { premix+expsum(n) on S[cur]; QK(n+1)->S[oth];
//                             prefetch K(n+2); barrier }
//   attn_av     : i-tile 16, ONE barrier/round software pipeline:
//                 body(n) = { AV(n-1) from Pp[oth]; premix(n)+postmix(n)
//                             S[cur]->Pp[cur]; QK(n+1)->S[oth]; prefetch
//                             K(n+2)/V(n+1); barrier }
// Both attn kernels use XCD-grouped 1-D grids: all 13 j-chunk (c) blocks of
// one (it,b) share id mod 8 -> same XCD -> l_ws/O_ws atomics stay L2-local
// (previous layout ping-ponged O lines through LLC: 247MB FETCH/dispatch).
// Raw s_barrier drains lgkmcnt only, keeping global prefetches in flight.
// ---------------------------------------------------------------------------

typedef __attribute__((ext_vector_type(8))) short short8;
typedef __attribute__((ext_vector_type(4))) float floatx4;

#define MFMA16(a, b, c) __builtin_amdgcn_mfma_f32_16x16x32_bf16(a, b, c, 0, 0, 0)
// LDS-only barrier: do NOT drain vmcnt (keeps K/V prefetch in flight).
#define BARLDS() __asm__ volatile("s_waitcnt lgkmcnt(0)\n\ts_barrier" ::: "memory")
#define LGKM0() __asm__ volatile("s_waitcnt lgkmcnt(0)" ::: "memory")

static __device__ __forceinline__ unsigned short f2bf(float f) {
  union { float f; unsigned u; } v; v.f = f;
  unsigned r = v.u + 0x7fffu + ((v.u >> 16) & 1u);
  return (unsigned short)(r >> 16);
}
static __device__ __forceinline__ float bf2f(unsigned short h) {
  union { unsigned u; float f; } v; v.u = ((unsigned)h) << 16;
  return v.f;
}

union S8U { short8 v; unsigned short u[8]; };

// ---------------- fp32 -> bf16 elementwise (8 elems/thread) -----------------
__global__ __launch_bounds__(256) void conv_bf16(const float* __restrict__ src,
                                                 unsigned short* __restrict__ dst,
                                                 int n8) {
  int tid = blockIdx.x * 256 + threadIdx.x;
  if (tid >= n8) return;
  const float4* s = (const float4*)src + (size_t)tid * 2;
  float4 a = s[0], b = s[1];
  S8U o;
  o.u[0] = f2bf(a.x); o.u[1] = f2bf(a.y); o.u[2] = f2bf(a.z); o.u[3] = f2bf(a.w);
  o.u[4] = f2bf(b.x); o.u[5] = f2bf(b.y); o.u[6] = f2bf(b.z); o.u[7] = f2bf(b.w);
  *(short8*)(dst + (size_t)tid * 8) = o.v;
}

// ---------------- transpose-convert W [K=1024][N] -> dst[N][1024] bf16 ------
__global__ __launch_bounds__(256) void transW(const float* __restrict__ src, int Ncols,
                                              unsigned short* __restrict__ dst, int dstRowOff) {
  __shared__ float sw[32][33];
  int n0 = blockIdx.x * 32, k0 = blockIdx.y * 32;
  int t = threadIdx.x;
  int lk = t >> 3, n4 = (t & 7) * 4;
  const float* s = src + (size_t)(k0 + lk) * Ncols + n0 + n4;
  sw[lk][n4 + 0] = s[0]; sw[lk][n4 + 1] = s[1];
  sw[lk][n4 + 2] = s[2]; sw[lk][n4 + 3] = s[3];
  __syncthreads();
  int ln = t >> 3, k4 = (t & 7) * 4;
  unsigned o0 = f2bf(sw[k4 + 0][ln]) | ((unsigned)f2bf(sw[k4 + 1][ln]) << 16);
  unsigned o1 = f2bf(sw[k4 + 2][ln]) | ((unsigned)f2bf(sw[k4 + 3][ln]) << 16);
  uint2 pk; pk.x = o0; pk.y = o1;
  *(uint2*)(dst + (size_t)(dstRowOff + n0 + ln) * 1024 + k0 + k4) = pk;
}

// ---------------- bf16 MFMA GEMM, direct-from-global fragments --------------
__global__ __launch_bounds__(256) void gemm_bt(const unsigned short* __restrict__ A,
                                               const unsigned short* __restrict__ BT,
                                               unsigned short* __restrict__ Cb,
                                               float* __restrict__ Cf,
                                               int M, int N, int K, int f32out) {
  int w = threadIdx.x >> 6, lane = threadIdx.x & 63;
  int quad = lane >> 4, l16 = lane & 15;
  int m0 = blockIdx.x * 128 + (w >> 1) * 64;
  int n0 = blockIdx.y * 128 + (w & 1) * 64;
  floatx4 acc[4][4];
#pragma unroll
  for (int i = 0; i < 4; i++)
#pragma unroll
    for (int j = 0; j < 4; j++) acc[i][j] = (floatx4){0.f, 0.f, 0.f, 0.f};

  for (int kk = 0; kk < K; kk += 32) {
    short8 af[4], bf[4];
#pragma unroll
    for (int t = 0; t < 4; t++) {
      af[t] = *(const short8*)(A + (size_t)(m0 + t * 16 + l16) * K + kk + quad * 8);
      bf[t] = *(const short8*)(BT + (size_t)(n0 + t * 16 + l16) * K + kk + quad * 8);
    }
#pragma unroll
    for (int mt = 0; mt < 4; mt++)
#pragma unroll
      for (int nt = 0; nt < 4; nt++) acc[mt][nt] = MFMA16(af[mt], bf[nt], acc[mt][nt]);
  }
#pragma unroll
  for (int mt = 0; mt < 4; mt++)
#pragma unroll
    for (int nt = 0; nt < 4; nt++)
#pragma unroll
      for (int r = 0; r < 4; r++) {
        size_t row = m0 + mt * 16 + quad * 4 + r;
        size_t col = n0 + nt * 16 + l16;
        if (f32out) Cf[row * N + col] = acc[mt][nt][r];
        else Cb[row * N + col] = f2bf(acc[mt][nt][r]);
      }
}

// ---------------- build K_ws [b][h][2064][64] bf16 --------------------------
__global__ __launch_bounds__(256) void fill_K(const unsigned short* __restrict__ qkv,
                                              const float* __restrict__ mem_k,
                                              unsigned short* __restrict__ Kw) {
  int tid = blockIdx.x * 256 + threadIdx.x;
  if (tid >= 2 * 16 * 2064 * 8) return;
  int d0 = (tid & 7) * 8;
  int j = (tid >> 3) % 2064;
  int h = ((tid >> 3) / 2064) & 15;
  int b = (tid >> 3) / (2064 * 16);
  S8U o;
  if (j < 16) {
    const float* s = mem_k + ((size_t)(h * 16 + j) * 64 + d0);
#pragma unroll
    for (int c = 0; c < 8; c++) o.u[c] = f2bf(s[c]);
  } else {
    o.v = *(const short8*)(qkv + (size_t)(b * 2048 + j - 16) * 3072 + 1024 + h * 64 + d0);
  }
  *(short8*)(Kw + ((size_t)(b * 16 + h) * 2064 + j) * 64 + d0) = o.v;
}

// ---------------- build Vt_ws [b][h][64][2064] bf16 (transposed) ------------
__global__ __launch_bounds__(256) void fill_Vt(const unsigned short* __restrict__ qkv,
                                               const float* __restrict__ mem_v,
                                               unsigned short* __restrict__ Vt) {
  __shared__ float sv[16][65];
  int jt = blockIdx.x, h = blockIdx.y, b = blockIdx.z;
  int t = threadIdx.x;
  int j = t >> 4, d0 = (t & 15) * 4;
  int jg = jt * 16 + j;
  float v0, v1, v2, v3;
  if (jg < 16) {
    const float* s = mem_v + ((size_t)(h * 16 + jg) * 64 + d0);
    v0 = s[0]; v1 = s[1]; v2 = s[2]; v3 = s[3];
  } else {
    const unsigned short* s = qkv + (size_t)(b * 2048 + jg - 16) * 3072 + 2048 + h * 64 + d0;
    v0 = bf2f(s[0]); v1 = bf2f(s[1]); v2 = bf2f(s[2]); v3 = bf2f(s[3]);
  }
  sv[j][d0 + 0] = v0; sv[j][d0 + 1] = v1; sv[j][d0 + 2] = v2; sv[j][d0 + 3] = v3;
  __syncthreads();
  int d = t >> 2, j4 = (t & 3) * 4;
  unsigned o0 = f2bf(sv[j4 + 0][d]) | ((unsigned)f2bf(sv[j4 + 1][d]) << 16);
  unsigned o1 = f2bf(sv[j4 + 2][d]) | ((unsigned)f2bf(sv[j4 + 3][d]) << 16);
  uint2 pk; pk.x = o0; pk.y = o1;
  *(uint2*)(Vt + ((size_t)(b * 16 + h) * 64 + d) * 2064 + jt * 16 + j4) = pk;
}

// ---------------------------------------------------------------------------
// attn_stats: l[b,i,k'] = sum over causal j of exp(S'[k',i,j]).
// i-tile 32, j-round 32, double-buffered S, ONE barrier per round.
// Grid 1-D 1664: id = (it + 64*b) + 128*c  (same (it,b) -> same XCD).
// Wave w: QK for head h=w (all 32 i); pre-mix + exp for rows i* = 2w,2w+1.
// S addr = i*776 + j*24 + h (i-pad 8 u16; 16B-aligned b128 at h-off 0/8).
// ---------------------------------------------------------------------------

#define ST_LOADK(KF, J0)                                                      \
  { _Pragma("unroll") for (int jt = 0; jt < 2; jt++) {                        \
      int jr = min((J0) + jt * 16 + l16, 2063);                               \
      const unsigned short* kp = Kb + (size_t)jr * 64 + quad * 8;             \
      KF[jt][0] = *(const short8*)kp;                                         \
      KF[jt][1] = *(const short8*)(kp + 32);                                  \
  } }

#define ST_QK(SDST, KF)                                                      \
  { _Pragma("unroll") for (int jt = 0; jt < 2; jt++)                         \
      _Pragma("unroll") for (int s = 0; s < 2; s++) {                        \
        floatx4 a = (floatx4){0.f, 0.f, 0.f, 0.f};                           \
        a = MFMA16(qa[s][0], KF[jt][0], a);                                  \
        a = MFMA16(qa[s][1], KF[jt][1], a);                                  \
        _Pragma("unroll") for (int r = 0; r < 4; r++)                        \
          (SDST)[(s * 16 + quad * 4 + r) * 776 + (jt * 16 + l16) * 24 + w] = \
              f2bf(a[r]);                                                    \
  } }

#define ST_BODY(SCUR, SOTH, KF_USE, KF_LOAD)                                 \
  { const int j0 = jc0 + n * 32;                                             \
    _Pragma("unroll") for (int u = 0; u < 4; u++) {                          \
      const int iloc = u >> 1, jt = u & 1, ii = w * 2 + iloc;                \
      const short8 bb =                                                      \
          *(const short8*)((SCUR) + ii * 776 + (jt * 16 + l16) * 24 + hoff); \
      floatx4 sp = (floatx4){0.f, 0.f, 0.f, 0.f};                            \
      sp = MFMA16(preA, bb, sp);                                             \
      const int jg = j0 + jt * 16 + l16;                                     \
      if (jg <= i0 + ii + 16) {                                              \
        _Pragma("unroll") for (int r = 0; r < 4; r++)                        \
          l_loc[iloc][r] += __expf(sp[r]);                                   \
      }                                                                      \
    }                                                                        \
    if (n + 1 < niter) ST_QK(SOTH, KF_USE);                                  \
    if (n + 2 < niter) ST_LOADK(KF_LOAD, jc0 + (n + 2) * 32);                \
    if (n + 1 < niter) BARLDS();                                             \
  }

__global__ __launch_bounds__(1024) void attn_stats(const unsigned short* __restrict__ qkv,
                                                   const unsigned short* __restrict__ Kw,
                                                   const float* __restrict__ pre,
                                                   float* __restrict__ l_ws) {
  const int id = blockIdx.x;
  const int c = id >> 7, g = id & 127, it = g & 63, b = g >> 6;
  const int i0 = it * 32;
  const int jmax = i0 + 48;          // exclusive causal bound (j <= i+16)
  const int jc0 = c * 160;
  if (jc0 >= jmax) return;
  const int jend = min(jmax, jc0 + 160);
  const int niter = (jend - jc0 + 31) >> 5;

  __shared__ unsigned short S_lds[2][32 * 776];  // 99,328 B

  const int tid = threadIdx.x, w = tid >> 6, lane = tid & 63;
  const int quad = lane >> 4, l16 = lane & 15;
  const int hoff = (quad < 2) ? quad * 8 : 0;
  unsigned short* const S0 = S_lds[0];
  unsigned short* const S1 = S_lds[1];

  short8 qa[2][2];
#pragma unroll
  for (int s = 0; s < 2; s++) {
    const unsigned short* p =
        qkv + (size_t)(b * 2048 + i0 + s * 16 + l16) * 3072 + w * 64 + quad * 8;
    qa[s][0] = *(const short8*)p;
    qa[s][1] = *(const short8*)(p + 32);
  }
  short8 preA;
#pragma unroll
  for (int jj = 0; jj < 8; jj++) {
    int h = quad * 8 + jj;
    preA[jj] = (short)((quad < 2) ? f2bf(pre[h * 16 + l16] * 0.125f) : 0);
  }
  const unsigned short* Kb = Kw + (size_t)(b * 16 + w) * 2064 * 64;

  float l_loc[2][4];
#pragma unroll
  for (int i4 = 0; i4 < 2; i4++)
#pragma unroll
    for (int r = 0; r < 4; r++) l_loc[i4][r] = 0.f;

  short8 kfA[2][2], kfB[2][2];
  ST_LOADK(kfA, jc0);
  ST_QK(S0, kfA);                       // QK(0) -> S[0]
  if (niter > 1) ST_LOADK(kfB, jc0 + 32);
  BARLDS();

  int n = 0;
  while (true) {
    ST_BODY(S0, S1, kfB, kfA);          // even round
    if (++n == niter) break;
    ST_BODY(S1, S0, kfA, kfB);          // odd round
    if (++n == niter) break;
  }

#pragma unroll
  for (int iloc = 0; iloc < 2; iloc++)
#pragma unroll
    for (int r = 0; r < 4; r++) {
      float v = l_loc[iloc][r];
      v += __shfl_xor(v, 1);
      v += __shfl_xor(v, 2);
      v += __shfl_xor(v, 4);
      v += __shfl_xor(v, 8);
      if (l16 == 0)
        atomicAdd(l_ws + ((size_t)(b * 2048 + i0 + w * 2 + iloc) * 16 + quad * 4 + r), v);
    }
}

// ---------------------------------------------------------------------------
// attn_av: recompute S', P=exp(S')/l, post-mix -> Pp, AV; atomicAdd O_ws.
// i-tile 16, j-round 32, double-buffered S AND Pp, ONE barrier per round:
//   body(n) = { AV(n-1) Pp[oth]*vf[oth]; premix(n) S[cur]->P; LGKM;
//               postmix(n) -> Pp[cur]; QK(n+1) -> S[oth]; prefetch K(n+2),
//               V(n+1); BARLDS }
// Grid 1-D 3328: id = (it + 128*b) + 256*c (same (it,b) -> same XCD).
// Wave w: QK head h=w; mix row i* = w; AV value head k2 = w.
// Pp addr = k2*648 + i*40 + j (AV A-frag layout, 16B-aligned b128 reads).
// ---------------------------------------------------------------------------

#define AV_LOADK(KF, J0)                                                      \
  { _Pragma("unroll") for (int jt = 0; jt < 2; jt++) {                        \
      int jr = min((J0) + jt * 16 + l16, 2063);                               \
      const unsigned short* kp = Kb + (size_t)jr * 64 + quad * 8;             \
      KF[jt][0] = *(const short8*)kp;                                         \
      KF[jt][1] = *(const short8*)(kp + 32);                                  \
  } }

#define AV_LOADV(VF, J0)                                                      \
  { const int jc = min((J0) + quad * 8, 2056);                                \
    _Pragma("unroll") for (int d = 0; d < 4; d++)                             \
      VF[d] = *(const short8*)(Vb + (size_t)(d * 16 + l16) * 2064 + jc); }

#define AV_QK(SDST, KF)                                                      \
  { _Pragma("unroll") for (int jt = 0; jt < 2; jt++) {                       \
      floatx4 a = (floatx4){0.f, 0.f, 0.f, 0.f};                             \
      a = MFMA16(qa[0], KF[jt][0], a);                                       \
      a = MFMA16(qa[1], KF[jt][1], a);                                       \
      _Pragma("unroll") for (int r = 0; r < 4; r++)                          \
        (SDST)[(quad * 4 + r) * 776 + (jt * 16 + l16) * 24 + w] = f2bf(a[r]); \
  } }

#define AV_MIX(SCUR, PPDST, J0)                                              \
  { _Pragma("unroll") for (int jt = 0; jt < 2; jt++) {                       \
      const int sc = w * 776 + (jt * 16 + l16) * 24;                         \
      const short8 bb = *(const short8*)((SCUR) + sc + hoff);                \
      floatx4 sp = (floatx4){0.f, 0.f, 0.f, 0.f};                            \
      sp = MFMA16(preA, bb, sp);                                             \
      const int jg = (J0) + jt * 16 + l16;                                   \
      const bool keep = jg <= i0 + w + 16;                                   \
      _Pragma("unroll") for (int r = 0; r < 4; r++)                          \
        (SCUR)[sc + quad * 4 + r] = f2bf(keep ? __expf(sp[r]) * rl[r] : 0.f);\
    }                                                                        \
    LGKM0(); /* own-wave P writes visible before re-read */                  \
    _Pragma("unroll") for (int jt = 0; jt < 2; jt++) {                       \
      const int sc = w * 776 + (jt * 16 + l16) * 24;                         \
      const short8 pf = *(const short8*)((SCUR) + sc + hoff);                \
      floatx4 pp = (floatx4){0.f, 0.f, 0.f, 0.f};                            \
      pp = MFMA16(postA, pf, pp);                                            \
      _Pragma("unroll") for (int r = 0; r < 4; r++)                          \
        (PPDST)[(quad * 4 + r) * 648 + w * 40 + jt * 16 + l16] = f2bf(pp[r]); \
  } }

#define AV_AV(PPSRC, VF)                                                     \
  { const short8 paf =                                                       \
        *(const short8*)((PPSRC) + w * 648 + l16 * 40 + quad * 8);           \
    _Pragma("unroll") for (int d = 0; d < 4; d++)                            \
      oacc[d] = MFMA16(paf, VF[d], oacc[d]); }

#define AV_BODY(SCUR, SOTH, PPCUR, PPOTH, KFOTH, KFCUR, VFOTH)               \
  { if (n > 0) AV_AV(PPOTH, VFOTH);                                          \
    AV_MIX(SCUR, PPCUR, jc0 + n * 32);                                       \
    if (n + 1 < niter) AV_QK(SOTH, KFOTH);                                   \
    if (n + 2 < niter) AV_LOADK(KFCUR, jc0 + (n + 2) * 32);                  \
    if (n + 1 < niter) AV_LOADV(VFOTH, jc0 + (n + 1) * 32);                  \
    BARLDS(); }

__global__ __launch_bounds__(1024) void attn_av(const unsigned short* __restrict__ qkv,
                                                const unsigned short* __restrict__ Kw,
                                                const unsigned short* __restrict__ Vt,
                                                const float* __restrict__ pre,
                                                const float* __restrict__ post,
                                                const float* __restrict__ l_ws,
                                                float* __restrict__ O_ws) {
  const int id = blockIdx.x;
  const int c = id >> 8, g = id & 255, it = g & 127, b = g >> 7;
  const int i0 = it * 16;
  const int jmax = i0 + 32;          // exclusive causal bound (j <= i+16)
  const int jc0 = c * 160;
  if (jc0 >= jmax) return;
  const int jend = min(jmax, jc0 + 160);
  const int niter = (jend - jc0 + 31) >> 5;

  __shared__ unsigned short S_lds[2][16 * 776];   // 49,664 B (S, then P)
  __shared__ unsigned short Pp_lds[2][16 * 648];  // 41,472 B

  const int tid = threadIdx.x, w = tid >> 6, lane = tid & 63;
  const int quad = lane >> 4, l16 = lane & 15;
  const int hoff = (quad < 2) ? quad * 8 : 0;
  unsigned short* const S0 = S_lds[0];
  unsigned short* const S1 = S_lds[1];
  unsigned short* const Pp0 = Pp_lds[0];
  unsigned short* const Pp1 = Pp_lds[1];

  short8 qa[2];
  {
    const unsigned short* p =
        qkv + (size_t)(b * 2048 + i0 + l16) * 3072 + w * 64 + quad * 8;
    qa[0] = *(const short8*)p;
    qa[1] = *(const short8*)(p + 32);
  }
  short8 preA, postA;
#pragma unroll
  for (int jj = 0; jj < 8; jj++) {
    int h = quad * 8 + jj;
    float pv = 0.f, qv = 0.f;
    if (quad < 2) { pv = pre[h * 16 + l16] * 0.125f; qv = post[h * 16 + l16]; }
    preA[jj] = (short)f2bf(pv);
    postA[jj] = (short)f2bf(qv);
  }
  float rl[4];
#pragma unroll
  for (int r = 0; r < 4; r++)
    rl[r] = 1.0f / l_ws[(size_t)(b * 2048 + i0 + w) * 16 + quad * 4 + r];

  floatx4 oacc[4];
#pragma unroll
  for (int d = 0; d < 4; d++) oacc[d] = (floatx4){0.f, 0.f, 0.f, 0.f};

  const unsigned short* Kb = Kw + (size_t)(b * 16 + w) * 2064 * 64;
  const unsigned short* Vb = Vt + (size_t)(b * 16 + w) * 64 * 2064;

  short8 kfA[2][2], kfB[2][2];
  short8 vfA[4], vfB[4];
  AV_LOADV(vfA, jc0);                   // vf(0) -> A (issues early)
  AV_LOADK(kfA, jc0);
  AV_QK(S0, kfA);                       // QK(0) -> S[0]
  if (niter > 1) AV_LOADK(kfB, jc0 + 32);
  BARLDS();

  int n = 0;
  while (true) {
    AV_BODY(S0, S1, Pp0, Pp1, kfB, kfA, vfB);   // even round
    if (++n == niter) { AV_AV(Pp0, vfA); break; }
    AV_BODY(S1, S0, Pp1, Pp0, kfA, kfB, vfA);   // odd round
    if (++n == niter) { AV_AV(Pp1, vfB); break; }
  }

  // ---- accumulate into O_ws fp32 (XCD-local lines via grid grouping) ----
#pragma unroll
  for (int d = 0; d < 4; d++)
#pragma unroll
    for (int r = 0; r < 4; r++)
      atomicAdd(O_ws + (size_t)(b * 2048 + i0 + quad * 4 + r) * 1024 +
                    w * 64 + d * 16 + l16,
                oacc[d][r]);
}

// ---------------------------------------------------------------------------
extern "C" void kernel_launch(void* const* d_in, const int* in_sizes, int n_in,
                              void* d_out, int out_size, void* d_ws, size_t ws_size,
                              hipStream_t stream) {
  (void)in_sizes; (void)n_in; (void)out_size; (void)ws_size;
  const float* x     = (const float*)d_in[0];
  const float* Wq    = (const float*)d_in[1];
  const float* Wkv   = (const float*)d_in[2];
  const float* Wo    = (const float*)d_in[3];
  const float* pre   = (const float*)d_in[4];
  const float* post  = (const float*)d_in[5];
  const float* mem_k = (const float*)d_in[6];
  const float* mem_v = (const float*)d_in[7];
  float* out = (float*)d_out;
  char* ws = (char*)d_ws;

  // Temporally-aliased workspace (total 67,239,936 B):
  //   [0, 16.8M):  xb(8M)+WbT(6M)+pad — dead after qkv gemm -> O_ws fp32 16M
  //   [16.8M, 41.9M): qkv bf16 — dead after attn_av -> WoT (2M)
  //   [41.9M, 50.4M): Kw ; [50.4M, 58.9M): Vt
  //   [58.9M, 67.2M): l_ws (256K, dead after attn_av) then attn_b bf16 (8M)
  unsigned short* xb     = (unsigned short*)(ws);
  unsigned short* WbT    = (unsigned short*)(ws + 8388608);
  float*          O_ws   = (float*)(ws);                     // 16,777,216 B
  unsigned short* qkv    = (unsigned short*)(ws + 16777216); // 25,165,824 B
  unsigned short* WoT    = (unsigned short*)(ws + 16777216); // 2 MB (post-attn)
  unsigned short* Kw     = (unsigned short*)(ws + 41943040); //  8,454,144 B
  unsigned short* Vt     = (unsigned short*)(ws + 50397184); //  8,454,144 B
  float*          l_ws   = (float*)(ws + 58851328);          //    262,144 B
  unsigned short* attn_b = (unsigned short*)(ws + 58851328); //  8,388,608 B

  conv_bf16<<<2048, 256, 0, stream>>>(x, xb, 524288);
  transW<<<dim3(32, 32), 256, 0, stream>>>(Wq, 1024, WbT, 0);
  transW<<<dim3(64, 32), 256, 0, stream>>>(Wkv, 2048, WbT, 1024);
  gemm_bt<<<dim3(32, 24), 256, 0, stream>>>(xb, WbT, qkv, nullptr, 4096, 3072, 1024, 0);
  fill_K<<<2064, 256, 0, stream>>>(qkv, mem_k, Kw);
  fill_Vt<<<dim3(129, 16, 2), 256, 0, stream>>>(qkv, mem_v, Vt);
  hipMemsetAsync(O_ws, 0, 16777216, stream);   // xb/WbT dead now
  hipMemsetAsync(l_ws, 0, 262144, stream);
  // XCD-grouped linear grids: id = g + (#g)*c keeps all c-chunks of one
  // (it,b) on the same XCD (id mod 8 constant) -> L2-local atomics.
  attn_stats<<<1664, 1024, 0, stream>>>(qkv, Kw, pre, l_ws);
  attn_av<<<3328, 1024, 0, stream>>>(qkv, Kw, Vt, pre, post, l_ws, O_ws);
  conv_bf16<<<2048, 256, 0, stream>>>(O_ws, attn_b, 524288);  // l_ws dead now
  transW<<<dim3(32, 32), 256, 0, stream>>>(Wo, 1024, WoT, 0); // qkv dead now
  gemm_bt<<<dim3(32, 8), 256, 0, stream>>>(attn_b, WoT, nullptr, out, 4096, 1024, 1024, 1);
}

// Round 2
// 494.785 us; speedup vs baseline: 1.2907x; 1.2907x over previous
//
#include <hip/hip_runtime.h>

// ---------------------------------------------------------------------------
// BoringAttention (talking-heads) on MI355X.
// Pipeline:
//   conv_bf16   : x fp32 -> xb bf16
//   transW x2   : Wq|Wkv -> WbT [3072][1024] bf16
//   gemm_bt     : xb @ W -> qkv bf16 [4096][3072] (q|k|v)
//   fill_K      : K_ws [b][h][2064][64] bf16 (mem_k prepended)
//   fill_Vt     : Vt_ws [b][h][64][2064] bf16 (transposed, mem_v prepended)
//   memset      : O_ws (fp32), l_ws (fp32)
//   attn_stats  : i-tile 32 (was 64), single-buffered S (49.7KB) -> 2 blk/CU
//   attn_av     : i-tile 16 (was 32), single-buffered S+Pp (45.6KB) -> 2 blk/CU
// Occupancy is the lever: round-0 ran 1 block/CU (91-99KB LDS) and every
// barrier/LDS round-trip was exposed (MfmaUtil 5.5%). Two blocks/CU lets one
// block's MFMA cover the other's barrier stalls (m114 co-scheduling).
// Grids are dim3(c, it, b) with c FASTEST: the j-chunks of one (it,b) tile
// are dispatch-adjacent -> run concurrently -> O_ws/l_ws atomic lines stay
// hot in cache (round-1 proved the alternative costs 4x WRITE_SIZE).
// Raw s_barrier drains lgkmcnt only, keeping K/V prefetches in flight.
// ---------------------------------------------------------------------------

typedef __attribute__((ext_vector_type(8))) short short8;
typedef __attribute__((ext_vector_type(4))) float floatx4;

#define MFMA16(a, b, c) __builtin_amdgcn_mfma_f32_16x16x32_bf16(a, b, c, 0, 0, 0)
// LDS-only barrier: do NOT drain vmcnt (keeps K/V prefetch in flight).
#define BARLDS() __asm__ volatile("s_waitcnt lgkmcnt(0)\n\ts_barrier" ::: "memory")
#define LGKM0() __asm__ volatile("s_waitcnt lgkmcnt(0)" ::: "memory")

static __device__ __forceinline__ unsigned short f2bf(float f) {
  union { float f; unsigned u; } v; v.f = f;
  unsigned r = v.u + 0x7fffu + ((v.u >> 16) & 1u);
  return (unsigned short)(r >> 16);
}
static __device__ __forceinline__ float bf2f(unsigned short h) {
  union { unsigned u; float f; } v; v.u = ((unsigned)h) << 16;
  return v.f;
}

union S8U { short8 v; unsigned short u[8]; };

// ---------------- fp32 -> bf16 elementwise (8 elems/thread) -----------------
__global__ __launch_bounds__(256) void conv_bf16(const float* __restrict__ src,
                                                 unsigned short* __restrict__ dst,
                                                 int n8) {
  int tid = blockIdx.x * 256 + threadIdx.x;
  if (tid >= n8) return;
  const float4* s = (const float4*)src + (size_t)tid * 2;
  float4 a = s[0], b = s[1];
  S8U o;
  o.u[0] = f2bf(a.x); o.u[1] = f2bf(a.y); o.u[2] = f2bf(a.z); o.u[3] = f2bf(a.w);
  o.u[4] = f2bf(b.x); o.u[5] = f2bf(b.y); o.u[6] = f2bf(b.z); o.u[7] = f2bf(b.w);
  *(short8*)(dst + (size_t)tid * 8) = o.v;
}

// ---------------- transpose-convert W [K=1024][N] -> dst[N][1024] bf16 ------
__global__ __launch_bounds__(256) void transW(const float* __restrict__ src, int Ncols,
                                              unsigned short* __restrict__ dst, int dstRowOff) {
  __shared__ float sw[32][33];
  int n0 = blockIdx.x * 32, k0 = blockIdx.y * 32;
  int t = threadIdx.x;
  int lk = t >> 3, n4 = (t & 7) * 4;
  const float* s = src + (size_t)(k0 + lk) * Ncols + n0 + n4;
  sw[lk][n4 + 0] = s[0]; sw[lk][n4 + 1] = s[1];
  sw[lk][n4 + 2] = s[2]; sw[lk][n4 + 3] = s[3];
  __syncthreads();
  int ln = t >> 3, k4 = (t & 7) * 4;
  unsigned o0 = f2bf(sw[k4 + 0][ln]) | ((unsigned)f2bf(sw[k4 + 1][ln]) << 16);
  unsigned o1 = f2bf(sw[k4 + 2][ln]) | ((unsigned)f2bf(sw[k4 + 3][ln]) << 16);
  uint2 pk; pk.x = o0; pk.y = o1;
  *(uint2*)(dst + (size_t)(dstRowOff + n0 + ln) * 1024 + k0 + k4) = pk;
}

// ---------------- bf16 MFMA GEMM, direct-from-global fragments --------------
__global__ __launch_bounds__(256) void gemm_bt(const unsigned short* __restrict__ A,
                                               const unsigned short* __restrict__ BT,
                                               unsigned short* __restrict__ Cb,
                                               float* __restrict__ Cf,
                                               int M, int N, int K, int f32out) {
  int w = threadIdx.x >> 6, lane = threadIdx.x & 63;
  int quad = lane >> 4, l16 = lane & 15;
  int m0 = blockIdx.x * 128 + (w >> 1) * 64;
  int n0 = blockIdx.y * 128 + (w & 1) * 64;
  floatx4 acc[4][4];
#pragma unroll
  for (int i = 0; i < 4; i++)
#pragma unroll
    for (int j = 0; j < 4; j++) acc[i][j] = (floatx4){0.f, 0.f, 0.f, 0.f};

  for (int kk = 0; kk < K; kk += 32) {
    short8 af[4], bf[4];
#pragma unroll
    for (int t = 0; t < 4; t++) {
      af[t] = *(const short8*)(A + (size_t)(m0 + t * 16 + l16) * K + kk + quad * 8);
      bf[t] = *(const short8*)(BT + (size_t)(n0 + t * 16 + l16) * K + kk + quad * 8);
    }
#pragma unroll
    for (int mt = 0; mt < 4; mt++)
#pragma unroll
      for (int nt = 0; nt < 4; nt++) acc[mt][nt] = MFMA16(af[mt], bf[nt], acc[mt][nt]);
  }
#pragma unroll
  for (int mt = 0; mt < 4; mt++)
#pragma unroll
    for (int nt = 0; nt < 4; nt++)
#pragma unroll
      for (int r = 0; r < 4; r++) {
        size_t row = m0 + mt * 16 + quad * 4 + r;
        size_t col = n0 + nt * 16 + l16;
        if (f32out) Cf[row * N + col] = acc[mt][nt][r];
        else Cb[row * N + col] = f2bf(acc[mt][nt][r]);
      }
}

// ---------------- build K_ws [b][h][2064][64] bf16 --------------------------
__global__ __launch_bounds__(256) void fill_K(const unsigned short* __restrict__ qkv,
                                              const float* __restrict__ mem_k,
                                              unsigned short* __restrict__ Kw) {
  int tid = blockIdx.x * 256 + threadIdx.x;
  if (tid >= 2 * 16 * 2064 * 8) return;
  int d0 = (tid & 7) * 8;
  int j = (tid >> 3) % 2064;
  int h = ((tid >> 3) / 2064) & 15;
  int b = (tid >> 3) / (2064 * 16);
  S8U o;
  if (j < 16) {
    const float* s = mem_k + ((size_t)(h * 16 + j) * 64 + d0);
#pragma unroll
    for (int c = 0; c < 8; c++) o.u[c] = f2bf(s[c]);
  } else {
    o.v = *(const short8*)(qkv + (size_t)(b * 2048 + j - 16) * 3072 + 1024 + h * 64 + d0);
  }
  *(short8*)(Kw + ((size_t)(b * 16 + h) * 2064 + j) * 64 + d0) = o.v;
}

// ---------------- build Vt_ws [b][h][64][2064] bf16 (transposed) ------------
__global__ __launch_bounds__(256) void fill_Vt(const unsigned short* __restrict__ qkv,
                                               const float* __restrict__ mem_v,
                                               unsigned short* __restrict__ Vt) {
  __shared__ float sv[16][65];
  int jt = blockIdx.x, h = blockIdx.y, b = blockIdx.z;
  int t = threadIdx.x;
  int j = t >> 4, d0 = (t & 15) * 4;
  int jg = jt * 16 + j;
  float v0, v1, v2, v3;
  if (jg < 16) {
    const float* s = mem_v + ((size_t)(h * 16 + jg) * 64 + d0);
    v0 = s[0]; v1 = s[1]; v2 = s[2]; v3 = s[3];
  } else {
    const unsigned short* s = qkv + (size_t)(b * 2048 + jg - 16) * 3072 + 2048 + h * 64 + d0;
    v0 = bf2f(s[0]); v1 = bf2f(s[1]); v2 = bf2f(s[2]); v3 = bf2f(s[3]);
  }
  sv[j][d0 + 0] = v0; sv[j][d0 + 1] = v1; sv[j][d0 + 2] = v2; sv[j][d0 + 3] = v3;
  __syncthreads();
  int d = t >> 2, j4 = (t & 3) * 4;
  unsigned o0 = f2bf(sv[j4 + 0][d]) | ((unsigned)f2bf(sv[j4 + 1][d]) << 16);
  unsigned o1 = f2bf(sv[j4 + 2][d]) | ((unsigned)f2bf(sv[j4 + 3][d]) << 16);
  uint2 pk; pk.x = o0; pk.y = o1;
  *(uint2*)(Vt + ((size_t)(b * 16 + h) * 64 + d) * 2064 + jt * 16 + j4) = pk;
}

// ---------------------------------------------------------------------------
// attn_stats: l[b,i,k'] = sum over causal j of exp(S'[k',i,j]).
// Grid (c<13, it<64, b<2), 1024 thr = 16 waves. i-tile 32, j-chunk 160.
// Single-buffered S (49,664 B) -> 2 blocks/CU. Two barriers per 32-j round.
// Wave w: QK for head h=w (all 32 i); pre-mix + exp for rows i* = 2w, 2w+1.
// S addr = i*776 + j*24 + h (j-stride 24 u16: 48B -> bank step 12 -> free
// 2-way; keeps 16B alignment for b128 reads at h-offset 0/8).
// ---------------------------------------------------------------------------
__global__ __launch_bounds__(1024) void attn_stats(const unsigned short* __restrict__ qkv,
                                                   const unsigned short* __restrict__ Kw,
                                                   const float* __restrict__ pre,
                                                   float* __restrict__ l_ws) {
  const int c = blockIdx.x, it = blockIdx.y, b = blockIdx.z;
  const int i0 = it * 32;
  const int jmax = i0 + 48;          // exclusive causal bound (j <= i+16)
  const int jc0 = c * 160;
  if (jc0 >= jmax) return;
  const int jend = min(jmax, jc0 + 160);
  const int niter = (jend - jc0 + 31) >> 5;

  __shared__ unsigned short S_lds[32 * 776];  // 49,664 B -> 2 blocks/CU

  const int tid = threadIdx.x, w = tid >> 6, lane = tid & 63;
  const int quad = lane >> 4, l16 = lane & 15;
  const int hoff = (quad < 2) ? quad * 8 : 0;

  short8 qa[2][2];
#pragma unroll
  for (int s = 0; s < 2; s++) {
    const unsigned short* p =
        qkv + (size_t)(b * 2048 + i0 + s * 16 + l16) * 3072 + w * 64 + quad * 8;
    qa[s][0] = *(const short8*)p;
    qa[s][1] = *(const short8*)(p + 32);
  }
  short8 preA;
#pragma unroll
  for (int jj = 0; jj < 8; jj++) {
    int h = quad * 8 + jj;
    preA[jj] = (short)((quad < 2) ? f2bf(pre[h * 16 + l16] * 0.125f) : 0);
  }
  const unsigned short* Kb = Kw + (size_t)(b * 16 + w) * 2064 * 64;

  float l_loc[2][4];
#pragma unroll
  for (int i4 = 0; i4 < 2; i4++)
#pragma unroll
    for (int r = 0; r < 4; r++) l_loc[i4][r] = 0.f;

  // K register prefetch: preload round 0
  short8 kf[2][2];
#pragma unroll
  for (int jt = 0; jt < 2; jt++) {
    int jr = min(jc0 + jt * 16 + l16, 2063);
    const unsigned short* kp = Kb + (size_t)jr * 64 + quad * 8;
    kf[jt][0] = *(const short8*)kp;
    kf[jt][1] = *(const short8*)(kp + 32);
  }

  for (int n = 0; n < niter; n++) {
    const int j0 = jc0 + n * 32;
    // ---- QK^T -> S_lds (bf16) ----
#pragma unroll
    for (int jt = 0; jt < 2; jt++)
#pragma unroll
      for (int s = 0; s < 2; s++) {
        floatx4 a = (floatx4){0.f, 0.f, 0.f, 0.f};
        a = MFMA16(qa[s][0], kf[jt][0], a);
        a = MFMA16(qa[s][1], kf[jt][1], a);
#pragma unroll
        for (int r = 0; r < 4; r++)
          S_lds[(s * 16 + quad * 4 + r) * 776 + (jt * 16 + l16) * 24 + w] = f2bf(a[r]);
      }
    // ---- prefetch next round's K (stays in flight across barriers) ----
    if (n + 1 < niter) {
      const int j0n = j0 + 32;
#pragma unroll
      for (int jt = 0; jt < 2; jt++) {
        int jr = min(j0n + jt * 16 + l16, 2063);
        const unsigned short* kp = Kb + (size_t)jr * 64 + quad * 8;
        kf[jt][0] = *(const short8*)kp;
        kf[jt][1] = *(const short8*)(kp + 32);
      }
    }
    BARLDS();
    // ---- pre-mix (16x16x32, zero-padded K) + exp accumulate ----
#pragma unroll
    for (int u = 0; u < 4; u++) {
      const int iloc = u >> 1, jt = u & 1, ii = w * 2 + iloc;
      const short8 bb = *(const short8*)(S_lds + ii * 776 + (jt * 16 + l16) * 24 + hoff);
      floatx4 sp = (floatx4){0.f, 0.f, 0.f, 0.f};
      sp = MFMA16(preA, bb, sp);
      const int jg = j0 + jt * 16 + l16;
      if (jg <= i0 + ii + 16) {
#pragma unroll
        for (int r = 0; r < 4; r++) l_loc[iloc][r] += __expf(sp[r]);
      }
    }
    if (n + 1 < niter) BARLDS();
  }
#pragma unroll
  for (int iloc = 0; iloc < 2; iloc++)
#pragma unroll
    for (int r = 0; r < 4; r++) {
      float v = l_loc[iloc][r];
      v += __shfl_xor(v, 1);
      v += __shfl_xor(v, 2);
      v += __shfl_xor(v, 4);
      v += __shfl_xor(v, 8);
      if (l16 == 0)
        atomicAdd(l_ws + ((size_t)(b * 2048 + i0 + w * 2 + iloc) * 16 + quad * 4 + r), v);
    }
}

// ---------------------------------------------------------------------------
// attn_av: recompute S', P=exp(S')/l (in place in S buffer), post-mix -> Pp,
// AV; atomicAdd O_ws fp32. Grid (c<13, it<128, b<2), 16 waves, i-tile 16.
// Single-buffered S (24,832 B) + Pp (20,736 B) = 45,568 B -> 2 blocks/CU.
// Wave w: QK head h=w; mixes for row i* = w; AV for value head k2=w.
// Pp addr = k2*648 + i*40 + j (A-frag layout for AV, 16B-aligned b128 reads).
// ---------------------------------------------------------------------------
__global__ __launch_bounds__(1024) void attn_av(const unsigned short* __restrict__ qkv,
                                                const unsigned short* __restrict__ Kw,
                                                const unsigned short* __restrict__ Vt,
                                                const float* __restrict__ pre,
                                                const float* __restrict__ post,
                                                const float* __restrict__ l_ws,
                                                float* __restrict__ O_ws) {
  const int c = blockIdx.x, it = blockIdx.y, b = blockIdx.z;
  const int i0 = it * 16;
  const int jmax = i0 + 32;          // exclusive causal bound (j <= i+16)
  const int jc0 = c * 160;
  if (jc0 >= jmax) return;
  const int jend = min(jmax, jc0 + 160);
  const int niter = (jend - jc0 + 31) >> 5;

  __shared__ unsigned short S_lds[16 * 776];   // 24,832 B (S, then P in place)
  __shared__ unsigned short Pp_lds[16 * 648];  // 20,736 B

  const int tid = threadIdx.x, w = tid >> 6, lane = tid & 63;
  const int quad = lane >> 4, l16 = lane & 15;
  const int hoff = (quad < 2) ? quad * 8 : 0;

  short8 qa[2];
  {
    const unsigned short* p =
        qkv + (size_t)(b * 2048 + i0 + l16) * 3072 + w * 64 + quad * 8;
    qa[0] = *(const short8*)p;
    qa[1] = *(const short8*)(p + 32);
  }
  short8 preA, postA;
#pragma unroll
  for (int jj = 0; jj < 8; jj++) {
    int h = quad * 8 + jj;
    float pv = 0.f, qv = 0.f;
    if (quad < 2) { pv = pre[h * 16 + l16] * 0.125f; qv = post[h * 16 + l16]; }
    preA[jj] = (short)f2bf(pv);
    postA[jj] = (short)f2bf(qv);
  }
  float rl[4];
#pragma unroll
  for (int r = 0; r < 4; r++)
    rl[r] = 1.0f / l_ws[(size_t)(b * 2048 + i0 + w) * 16 + quad * 4 + r];

  floatx4 oacc[4];
#pragma unroll
  for (int d = 0; d < 4; d++) oacc[d] = (floatx4){0.f, 0.f, 0.f, 0.f};

  const unsigned short* Kb = Kw + (size_t)(b * 16 + w) * 2064 * 64;
  const unsigned short* Vb = Vt + (size_t)(b * 16 + w) * 64 * 2064;

  short8 kf[2][2];
#pragma unroll
  for (int jt = 0; jt < 2; jt++) {
    int jr = min(jc0 + jt * 16 + l16, 2063);
    const unsigned short* kp = Kb + (size_t)jr * 64 + quad * 8;
    kf[jt][0] = *(const short8*)kp;
    kf[jt][1] = *(const short8*)(kp + 32);
  }

  for (int n = 0; n < niter; n++) {
    const int j0 = jc0 + n * 32;
    // ---- V fragments for this round (independent; issues early) ----
    short8 vf[4];
    {
      const int jc = min(j0 + quad * 8, 2056);
#pragma unroll
      for (int d = 0; d < 4; d++)
        vf[d] = *(const short8*)(Vb + (size_t)(d * 16 + l16) * 2064 + jc);
    }
    // ---- QK^T -> S_lds ----
#pragma unroll
    for (int jt = 0; jt < 2; jt++) {
      floatx4 a = (floatx4){0.f, 0.f, 0.f, 0.f};
      a = MFMA16(qa[0], kf[jt][0], a);
      a = MFMA16(qa[1], kf[jt][1], a);
#pragma unroll
      for (int r = 0; r < 4; r++)
        S_lds[(quad * 4 + r) * 776 + (jt * 16 + l16) * 24 + w] = f2bf(a[r]);
    }
    // ---- prefetch next K ----
    if (n + 1 < niter) {
      const int j0n = j0 + 32;
#pragma unroll
      for (int jt = 0; jt < 2; jt++) {
        int jr = min(j0n + jt * 16 + l16, 2063);
        const unsigned short* kp = Kb + (size_t)jr * 64 + quad * 8;
        kf[jt][0] = *(const short8*)kp;
        kf[jt][1] = *(const short8*)(kp + 32);
      }
    }
    BARLDS();
    // ---- pre-mix + exp/l -> P (in place, wave-private row i*=w) ----
#pragma unroll
    for (int jt = 0; jt < 2; jt++) {
      const int sc = w * 776 + (jt * 16 + l16) * 24;
      const short8 bb = *(const short8*)(S_lds + sc + hoff);
      floatx4 sp = (floatx4){0.f, 0.f, 0.f, 0.f};
      sp = MFMA16(preA, bb, sp);
      const int jg = j0 + jt * 16 + l16;
      const bool keep = jg <= (i0 + w + 16);
#pragma unroll
      for (int r = 0; r < 4; r++)
        S_lds[sc + quad * 4 + r] = f2bf(keep ? __expf(sp[r]) * rl[r] : 0.f);
    }
    LGKM0();  // own-wave P writes visible before re-read
    // ---- post-mix -> Pp (AV A-frag layout) ----
#pragma unroll
    for (int jt = 0; jt < 2; jt++) {
      const int sc = w * 776 + (jt * 16 + l16) * 24;
      const short8 pf = *(const short8*)(S_lds + sc + hoff);
      floatx4 pp = (floatx4){0.f, 0.f, 0.f, 0.f};
      pp = MFMA16(postA, pf, pp);
#pragma unroll
      for (int r = 0; r < 4; r++)
        Pp_lds[(quad * 4 + r) * 648 + w * 40 + jt * 16 + l16] = f2bf(pp[r]);
    }
    BARLDS();
    // ---- AV: wave w = value head k2=w, K = 32 j's ----
    {
      const short8 paf = *(const short8*)(Pp_lds + w * 648 + l16 * 40 + quad * 8);
#pragma unroll
      for (int d = 0; d < 4; d++) oacc[d] = MFMA16(paf, vf[d], oacc[d]);
    }
  }
  // ---- accumulate into O_ws fp32 ----
#pragma unroll
  for (int d = 0; d < 4; d++)
#pragma unroll
    for (int r = 0; r < 4; r++)
      atomicAdd(O_ws + (size_t)(b * 2048 + i0 + quad * 4 + r) * 1024 +
                    w * 64 + d * 16 + l16,
                oacc[d][r]);
}

// ---------------------------------------------------------------------------
extern "C" void kernel_launch(void* const* d_in, const int* in_sizes, int n_in,
                              void* d_out, int out_size, void* d_ws, size_t ws_size,
                              hipStream_t stream) {
  (void)in_sizes; (void)n_in; (void)out_size; (void)ws_size;
  const float* x     = (const float*)d_in[0];
  const float* Wq    = (const float*)d_in[1];
  const float* Wkv   = (const float*)d_in[2];
  const float* Wo    = (const float*)d_in[3];
  const float* pre   = (const float*)d_in[4];
  const float* post  = (const float*)d_in[5];
  const float* mem_k = (const float*)d_in[6];
  const float* mem_v = (const float*)d_in[7];
  float* out = (float*)d_out;
  char* ws = (char*)d_ws;

  // Temporally-aliased workspace (total 67,239,936 B):
  //   [0, 16.8M):  xb(8M)+WbT(6M)+pad — dead after qkv gemm -> O_ws fp32 16M
  //   [16.8M, 41.9M): qkv bf16 — dead after attn_av -> WoT (2M)
  //   [41.9M, 50.4M): Kw ; [50.4M, 58.9M): Vt
  //   [58.9M, 67.2M): l_ws (256K, dead after attn_av) then attn_b bf16 (8M)
  unsigned short* xb     = (unsigned short*)(ws);
  unsigned short* WbT    = (unsigned short*)(ws + 8388608);
  float*          O_ws   = (float*)(ws);                     // 16,777,216 B
  unsigned short* qkv    = (unsigned short*)(ws + 16777216); // 25,165,824 B
  unsigned short* WoT    = (unsigned short*)(ws + 16777216); // 2 MB (post-attn)
  unsigned short* Kw     = (unsigned short*)(ws + 41943040); //  8,454,144 B
  unsigned short* Vt     = (unsigned short*)(ws + 50397184); //  8,454,144 B
  float*          l_ws   = (float*)(ws + 58851328);          //    262,144 B
  unsigned short* attn_b = (unsigned short*)(ws + 58851328); //  8,388,608 B

  conv_bf16<<<2048, 256, 0, stream>>>(x, xb, 524288);
  transW<<<dim3(32, 32), 256, 0, stream>>>(Wq, 1024, WbT, 0);
  transW<<<dim3(64, 32), 256, 0, stream>>>(Wkv, 2048, WbT, 1024);
  gemm_bt<<<dim3(32, 24), 256, 0, stream>>>(xb, WbT, qkv, nullptr, 4096, 3072, 1024, 0);
  fill_K<<<2064, 256, 0, stream>>>(qkv, mem_k, Kw);
  fill_Vt<<<dim3(129, 16, 2), 256, 0, stream>>>(qkv, mem_v, Vt);
  hipMemsetAsync(O_ws, 0, 16777216, stream);   // xb/WbT dead now
  hipMemsetAsync(l_ws, 0, 262144, stream);
  attn_stats<<<dim3(13, 64, 2), 1024, 0, stream>>>(qkv, Kw, pre, l_ws);
  attn_av<<<dim3(13, 128, 2), 1024, 0, stream>>>(qkv, Kw, Vt, pre, post, l_ws, O_ws);
  conv_bf16<<<2048, 256, 0, stream>>>(O_ws, attn_b, 524288);  // l_ws dead now
  transW<<<dim3(32, 32), 256, 0, stream>>>(Wo, 1024, WoT, 0); // qkv dead now
  gemm_bt<<<dim3(32, 8), 256, 0, stream>>>(attn_b, WoT, nullptr, out, 4096, 1024, 1024, 1);
}

// Round 3
// 420.032 us; speedup vs baseline: 1.5204x; 1.1780x over previous
//
#include <hip/hip_runtime.h>

// ---------------------------------------------------------------------------
// BoringAttention (talking-heads) on MI355X.
// Pipeline:
//   conv_bf16   : x fp32 -> xb bf16
//   transW x2   : Wq|Wkv -> WbT [3072][1024] bf16
//   gemm_bt     : xb @ W -> qkv bf16 [4096][3072] (q|k|v)   [LDS-staged 128^2]
//   fill_K      : K_ws [b][h][2064][64] bf16 (mem_k prepended)
//   fill_Vt     : Vt_ws [b][h][64][2064] bf16 (transposed, mem_v prepended)
//   memset      : O_ws (fp32), l_ws (fp32)
//   attn_stats  : i-tile 32, single-buffered S (49.7KB) -> 2 blk/CU
//   attn_av     : i-tile 32 (round-0 best: 195us), S+Pp 91KB -> 1 blk/CU
// Round-0/2 A/B showed: per-round wall scales with blocks/CU but traffic
// scales with 1/i-tile; i-tile-32 attn_av (round 0) is the best measured
// point. GEMMs were the un-staged outlier (direct-global fragments ~300TF);
// now classic reg->LDS staged 128x128 tile, padded rows (40 elems) for
// <=2-way bank conflicts, next-K-tile global loads issued under MFMAs.
// Grids dim3(c, it, b) with c FASTEST: same-tile j-chunks dispatch-adjacent
// -> O_ws/l_ws atomic lines stay cache-hot (round-1 proved 4x WRITE blowup
// otherwise). Raw s_barrier drains lgkmcnt only (K/V prefetch in flight).
// ---------------------------------------------------------------------------

typedef __attribute__((ext_vector_type(8))) short short8;
typedef __attribute__((ext_vector_type(4))) float floatx4;

#define MFMA16(a, b, c) __builtin_amdgcn_mfma_f32_16x16x32_bf16(a, b, c, 0, 0, 0)
// LDS-only barrier: do NOT drain vmcnt (keeps K/V prefetch in flight).
#define BARLDS() __asm__ volatile("s_waitcnt lgkmcnt(0)\n\ts_barrier" ::: "memory")
#define LGKM0() __asm__ volatile("s_waitcnt lgkmcnt(0)" ::: "memory")

static __device__ __forceinline__ unsigned short f2bf(float f) {
  union { float f; unsigned u; } v; v.f = f;
  unsigned r = v.u + 0x7fffu + ((v.u >> 16) & 1u);
  return (unsigned short)(r >> 16);
}
static __device__ __forceinline__ float bf2f(unsigned short h) {
  union { unsigned u; float f; } v; v.u = ((unsigned)h) << 16;
  return v.f;
}

union S8U { short8 v; unsigned short u[8]; };

// ---------------- fp32 -> bf16 elementwise (8 elems/thread) -----------------
__global__ __launch_bounds__(256) void conv_bf16(const float* __restrict__ src,
                                                 unsigned short* __restrict__ dst,
                                                 int n8) {
  int tid = blockIdx.x * 256 + threadIdx.x;
  if (tid >= n8) return;
  const float4* s = (const float4*)src + (size_t)tid * 2;
  float4 a = s[0], b = s[1];
  S8U o;
  o.u[0] = f2bf(a.x); o.u[1] = f2bf(a.y); o.u[2] = f2bf(a.z); o.u[3] = f2bf(a.w);
  o.u[4] = f2bf(b.x); o.u[5] = f2bf(b.y); o.u[6] = f2bf(b.z); o.u[7] = f2bf(b.w);
  *(short8*)(dst + (size_t)tid * 8) = o.v;
}

// ---------------- transpose-convert W [K=1024][N] -> dst[N][1024] bf16 ------
__global__ __launch_bounds__(256) void transW(const float* __restrict__ src, int Ncols,
                                              unsigned short* __restrict__ dst, int dstRowOff) {
  __shared__ float sw[32][33];
  int n0 = blockIdx.x * 32, k0 = blockIdx.y * 32;
  int t = threadIdx.x;
  int lk = t >> 3, n4 = (t & 7) * 4;
  const float* s = src + (size_t)(k0 + lk) * Ncols + n0 + n4;
  sw[lk][n4 + 0] = s[0]; sw[lk][n4 + 1] = s[1];
  sw[lk][n4 + 2] = s[2]; sw[lk][n4 + 3] = s[3];
  __syncthreads();
  int ln = t >> 3, k4 = (t & 7) * 4;
  unsigned o0 = f2bf(sw[k4 + 0][ln]) | ((unsigned)f2bf(sw[k4 + 1][ln]) << 16);
  unsigned o1 = f2bf(sw[k4 + 2][ln]) | ((unsigned)f2bf(sw[k4 + 3][ln]) << 16);
  uint2 pk; pk.x = o0; pk.y = o1;
  *(uint2*)(dst + (size_t)(dstRowOff + n0 + ln) * 1024 + k0 + k4) = pk;
}

// ---------------- bf16 MFMA GEMM, LDS-staged 128x128 tile -------------------
// Classic 2-barrier loop: {sync; reg->LDS; sync; issue next global loads;
// ds_read frags; 16 MFMA}. LDS rows padded to 40 elems (80B): write pattern
// <=2-way, b128 frag reads ~conflict-free. Next-tile loads fly under MFMAs.
__global__ __launch_bounds__(256) void gemm_bt(const unsigned short* __restrict__ A,
                                               const unsigned short* __restrict__ BT,
                                               unsigned short* __restrict__ Cb,
                                               float* __restrict__ Cf,
                                               int M, int N, int K, int f32out) {
  __shared__ unsigned short Al[128 * 40];
  __shared__ unsigned short Bl[128 * 40];
  const int t = threadIdx.x;
  const int w = t >> 6, lane = t & 63;
  const int quad = lane >> 4, l16 = lane & 15;
  const int mb = blockIdx.x * 128, nb = blockIdx.y * 128;
  const int m0 = (w >> 1) * 64, n0 = (w & 1) * 64;
  // staging: thread t owns row srow = t>>1, 32B half scol = (t&1)*16
  const int srow = t >> 1, scol = (t & 1) * 16;
  const unsigned short* Ag = A + (size_t)(mb + srow) * K + scol;
  const unsigned short* Bg = BT + (size_t)(nb + srow) * K + scol;
  unsigned short* Aw = Al + srow * 40 + scol;
  unsigned short* Bw = Bl + srow * 40 + scol;

  floatx4 acc[4][4];
#pragma unroll
  for (int i = 0; i < 4; i++)
#pragma unroll
    for (int j = 0; j < 4; j++) acc[i][j] = (floatx4){0.f, 0.f, 0.f, 0.f};

  short8 a0 = *(const short8*)(Ag);
  short8 a1 = *(const short8*)(Ag + 8);
  short8 b0 = *(const short8*)(Bg);
  short8 b1 = *(const short8*)(Bg + 8);

  for (int kk = 0; kk < K; kk += 32) {
    __syncthreads();                       // prev-iter LDS reads complete
    *(short8*)(Aw) = a0; *(short8*)(Aw + 8) = a1;
    *(short8*)(Bw) = b0; *(short8*)(Bw + 8) = b1;
    __syncthreads();                       // tile visible to all waves
    if (kk + 32 < K) {                     // next-tile loads: in flight under MFMAs
      a0 = *(const short8*)(Ag + kk + 32);
      a1 = *(const short8*)(Ag + kk + 40);
      b0 = *(const short8*)(Bg + kk + 32);
      b1 = *(const short8*)(Bg + kk + 40);
    }
    short8 af[4], bf[4];
#pragma unroll
    for (int s = 0; s < 4; s++) {
      af[s] = *(const short8*)(Al + (m0 + s * 16 + l16) * 40 + quad * 8);
      bf[s] = *(const short8*)(Bl + (n0 + s * 16 + l16) * 40 + quad * 8);
    }
#pragma unroll
    for (int mt = 0; mt < 4; mt++)
#pragma unroll
      for (int nt = 0; nt < 4; nt++) acc[mt][nt] = MFMA16(af[mt], bf[nt], acc[mt][nt]);
  }
#pragma unroll
  for (int mt = 0; mt < 4; mt++)
#pragma unroll
    for (int nt = 0; nt < 4; nt++)
#pragma unroll
      for (int r = 0; r < 4; r++) {
        size_t row = mb + m0 + mt * 16 + quad * 4 + r;
        size_t col = nb + n0 + nt * 16 + l16;
        if (f32out) Cf[row * N + col] = acc[mt][nt][r];
        else Cb[row * N + col] = f2bf(acc[mt][nt][r]);
      }
}

// ---------------- build K_ws [b][h][2064][64] bf16 --------------------------
__global__ __launch_bounds__(256) void fill_K(const unsigned short* __restrict__ qkv,
                                              const float* __restrict__ mem_k,
                                              unsigned short* __restrict__ Kw) {
  int tid = blockIdx.x * 256 + threadIdx.x;
  if (tid >= 2 * 16 * 2064 * 8) return;
  int d0 = (tid & 7) * 8;
  int j = (tid >> 3) % 2064;
  int h = ((tid >> 3) / 2064) & 15;
  int b = (tid >> 3) / (2064 * 16);
  S8U o;
  if (j < 16) {
    const float* s = mem_k + ((size_t)(h * 16 + j) * 64 + d0);
#pragma unroll
    for (int c = 0; c < 8; c++) o.u[c] = f2bf(s[c]);
  } else {
    o.v = *(const short8*)(qkv + (size_t)(b * 2048 + j - 16) * 3072 + 1024 + h * 64 + d0);
  }
  *(short8*)(Kw + ((size_t)(b * 16 + h) * 2064 + j) * 64 + d0) = o.v;
}

// ---------------- build Vt_ws [b][h][64][2064] bf16 (transposed) ------------
__global__ __launch_bounds__(256) void fill_Vt(const unsigned short* __restrict__ qkv,
                                               const float* __restrict__ mem_v,
                                               unsigned short* __restrict__ Vt) {
  __shared__ float sv[16][65];
  int jt = blockIdx.x, h = blockIdx.y, b = blockIdx.z;
  int t = threadIdx.x;
  int j = t >> 4, d0 = (t & 15) * 4;
  int jg = jt * 16 + j;
  float v0, v1, v2, v3;
  if (jg < 16) {
    const float* s = mem_v + ((size_t)(h * 16 + jg) * 64 + d0);
    v0 = s[0]; v1 = s[1]; v2 = s[2]; v3 = s[3];
  } else {
    const unsigned short* s = qkv + (size_t)(b * 2048 + jg - 16) * 3072 + 2048 + h * 64 + d0;
    v0 = bf2f(s[0]); v1 = bf2f(s[1]); v2 = bf2f(s[2]); v3 = bf2f(s[3]);
  }
  sv[j][d0 + 0] = v0; sv[j][d0 + 1] = v1; sv[j][d0 + 2] = v2; sv[j][d0 + 3] = v3;
  __syncthreads();
  int d = t >> 2, j4 = (t & 3) * 4;
  unsigned o0 = f2bf(sv[j4 + 0][d]) | ((unsigned)f2bf(sv[j4 + 1][d]) << 16);
  unsigned o1 = f2bf(sv[j4 + 2][d]) | ((unsigned)f2bf(sv[j4 + 3][d]) << 16);
  uint2 pk; pk.x = o0; pk.y = o1;
  *(uint2*)(Vt + ((size_t)(b * 16 + h) * 64 + d) * 2064 + jt * 16 + j4) = pk;
}

// ---------------------------------------------------------------------------
// attn_stats: l[b,i,k'] = sum over causal j of exp(S'[k',i,j]).
// Grid (c<13, it<64, b<2), 1024 thr = 16 waves. i-tile 32, j-chunk 160.
// Single-buffered S (49,664 B) -> 2 blocks/CU. Two barriers per 32-j round.
// Wave w: QK for head h=w (all 32 i); pre-mix + exp for rows i* = 2w, 2w+1.
// S addr = i*776 + j*24 + h.
// ---------------------------------------------------------------------------
__global__ __launch_bounds__(1024) void attn_stats(const unsigned short* __restrict__ qkv,
                                                   const unsigned short* __restrict__ Kw,
                                                   const float* __restrict__ pre,
                                                   float* __restrict__ l_ws) {
  const int c = blockIdx.x, it = blockIdx.y, b = blockIdx.z;
  const int i0 = it * 32;
  const int jmax = i0 + 48;          // exclusive causal bound (j <= i+16)
  const int jc0 = c * 160;
  if (jc0 >= jmax) return;
  const int jend = min(jmax, jc0 + 160);
  const int niter = (jend - jc0 + 31) >> 5;

  __shared__ unsigned short S_lds[32 * 776];  // 49,664 B -> 2 blocks/CU

  const int tid = threadIdx.x, w = tid >> 6, lane = tid & 63;
  const int quad = lane >> 4, l16 = lane & 15;
  const int hoff = (quad < 2) ? quad * 8 : 0;

  short8 qa[2][2];
#pragma unroll
  for (int s = 0; s < 2; s++) {
    const unsigned short* p =
        qkv + (size_t)(b * 2048 + i0 + s * 16 + l16) * 3072 + w * 64 + quad * 8;
    qa[s][0] = *(const short8*)p;
    qa[s][1] = *(const short8*)(p + 32);
  }
  short8 preA;
#pragma unroll
  for (int jj = 0; jj < 8; jj++) {
    int h = quad * 8 + jj;
    preA[jj] = (short)((quad < 2) ? f2bf(pre[h * 16 + l16] * 0.125f) : 0);
  }
  const unsigned short* Kb = Kw + (size_t)(b * 16 + w) * 2064 * 64;

  float l_loc[2][4];
#pragma unroll
  for (int i4 = 0; i4 < 2; i4++)
#pragma unroll
    for (int r = 0; r < 4; r++) l_loc[i4][r] = 0.f;

  // K register prefetch: preload round 0
  short8 kf[2][2];
#pragma unroll
  for (int jt = 0; jt < 2; jt++) {
    int jr = min(jc0 + jt * 16 + l16, 2063);
    const unsigned short* kp = Kb + (size_t)jr * 64 + quad * 8;
    kf[jt][0] = *(const short8*)kp;
    kf[jt][1] = *(const short8*)(kp + 32);
  }

  for (int n = 0; n < niter; n++) {
    const int j0 = jc0 + n * 32;
    // ---- QK^T -> S_lds (bf16) ----
#pragma unroll
    for (int jt = 0; jt < 2; jt++)
#pragma unroll
      for (int s = 0; s < 2; s++) {
        floatx4 a = (floatx4){0.f, 0.f, 0.f, 0.f};
        a = MFMA16(qa[s][0], kf[jt][0], a);
        a = MFMA16(qa[s][1], kf[jt][1], a);
#pragma unroll
        for (int r = 0; r < 4; r++)
          S_lds[(s * 16 + quad * 4 + r) * 776 + (jt * 16 + l16) * 24 + w] = f2bf(a[r]);
      }
    // ---- prefetch next round's K (stays in flight across barriers) ----
    if (n + 1 < niter) {
      const int j0n = j0 + 32;
#pragma unroll
      for (int jt = 0; jt < 2; jt++) {
        int jr = min(j0n + jt * 16 + l16, 2063);
        const unsigned short* kp = Kb + (size_t)jr * 64 + quad * 8;
        kf[jt][0] = *(const short8*)kp;
        kf[jt][1] = *(const short8*)(kp + 32);
      }
    }
    BARLDS();
    // ---- pre-mix (16x16x32, zero-padded K) + exp accumulate ----
#pragma unroll
    for (int u = 0; u < 4; u++) {
      const int iloc = u >> 1, jt = u & 1, ii = w * 2 + iloc;
      const short8 bb = *(const short8*)(S_lds + ii * 776 + (jt * 16 + l16) * 24 + hoff);
      floatx4 sp = (floatx4){0.f, 0.f, 0.f, 0.f};
      sp = MFMA16(preA, bb, sp);
      const int jg = j0 + jt * 16 + l16;
      if (jg <= i0 + ii + 16) {
#pragma unroll
        for (int r = 0; r < 4; r++) l_loc[iloc][r] += __expf(sp[r]);
      }
    }
    if (n + 1 < niter) BARLDS();
  }
#pragma unroll
  for (int iloc = 0; iloc < 2; iloc++)
#pragma unroll
    for (int r = 0; r < 4; r++) {
      float v = l_loc[iloc][r];
      v += __shfl_xor(v, 1);
      v += __shfl_xor(v, 2);
      v += __shfl_xor(v, 4);
      v += __shfl_xor(v, 8);
      if (l16 == 0)
        atomicAdd(l_ws + ((size_t)(b * 2048 + i0 + w * 2 + iloc) * 16 + quad * 4 + r), v);
    }
}

// ---------------------------------------------------------------------------
// attn_av: recompute S', P=exp(S')/l (in place in S buffer), post-mix -> Pp,
// AV; atomicAdd O_ws fp32. Grid (c<13, it<64, b<2), 16 waves, i-tile 32.
// (round-0 best-measured config: 195us)
// Wave w: QK head h=w; mixes for rows i* = 2w..2w+1; AV for value head k2=w.
// Pp addr = k2*1288 + i*40 + j (A-frag layout for AV, 16B-aligned b128 reads).
// ---------------------------------------------------------------------------
__global__ __launch_bounds__(1024) void attn_av(const unsigned short* __restrict__ qkv,
                                                const unsigned short* __restrict__ Kw,
                                                const unsigned short* __restrict__ Vt,
                                                const float* __restrict__ pre,
                                                const float* __restrict__ post,
                                                const float* __restrict__ l_ws,
                                                float* __restrict__ O_ws) {
  const int c = blockIdx.x, it = blockIdx.y, b = blockIdx.z;
  const int i0 = it * 32;
  const int jmax = i0 + 48;
  const int jc0 = c * 160;
  if (jc0 >= jmax) return;
  const int jend = min(jmax, jc0 + 160);
  const int niter = (jend - jc0 + 31) >> 5;

  __shared__ unsigned short S_lds[32 * 776];    // 49,664 B (S, then P in place)
  __shared__ unsigned short Pp_lds[16 * 1288];  // 41,216 B

  const int tid = threadIdx.x, w = tid >> 6, lane = tid & 63;
  const int quad = lane >> 4, l16 = lane & 15;
  const int hoff = (quad < 2) ? quad * 8 : 0;

  short8 qa[2][2];
#pragma unroll
  for (int s = 0; s < 2; s++) {
    const unsigned short* p =
        qkv + (size_t)(b * 2048 + i0 + s * 16 + l16) * 3072 + w * 64 + quad * 8;
    qa[s][0] = *(const short8*)p;
    qa[s][1] = *(const short8*)(p + 32);
  }
  short8 preA, postA;
#pragma unroll
  for (int jj = 0; jj < 8; jj++) {
    int h = quad * 8 + jj;
    float pv = 0.f, qv = 0.f;
    if (quad < 2) { pv = pre[h * 16 + l16] * 0.125f; qv = post[h * 16 + l16]; }
    preA[jj] = (short)f2bf(pv);
    postA[jj] = (short)f2bf(qv);
  }
  float rl[2][4];
#pragma unroll
  for (int iloc = 0; iloc < 2; iloc++)
#pragma unroll
    for (int r = 0; r < 4; r++)
      rl[iloc][r] = 1.0f / l_ws[(size_t)(b * 2048 + i0 + w * 2 + iloc) * 16 + quad * 4 + r];

  floatx4 oacc[2][4];
#pragma unroll
  for (int g = 0; g < 2; g++)
#pragma unroll
    for (int d = 0; d < 4; d++) oacc[g][d] = (floatx4){0.f, 0.f, 0.f, 0.f};

  const unsigned short* Kb = Kw + (size_t)(b * 16 + w) * 2064 * 64;
  const unsigned short* Vb = Vt + (size_t)(b * 16 + w) * 64 * 2064;

  short8 kf[2][2];
#pragma unroll
  for (int jt = 0; jt < 2; jt++) {
    int jr = min(jc0 + jt * 16 + l16, 2063);
    const unsigned short* kp = Kb + (size_t)jr * 64 + quad * 8;
    kf[jt][0] = *(const short8*)kp;
    kf[jt][1] = *(const short8*)(kp + 32);
  }

  for (int n = 0; n < niter; n++) {
    const int j0 = jc0 + n * 32;
    // ---- V fragments for this iteration (independent; issues early) ----
    short8 vf[4];
    {
      const int jc = min(j0 + quad * 8, 2056);
#pragma unroll
      for (int d = 0; d < 4; d++)
        vf[d] = *(const short8*)(Vb + (size_t)(d * 16 + l16) * 2064 + jc);
    }
    // ---- QK^T -> S_lds ----
#pragma unroll
    for (int jt = 0; jt < 2; jt++)
#pragma unroll
      for (int s = 0; s < 2; s++) {
        floatx4 a = (floatx4){0.f, 0.f, 0.f, 0.f};
        a = MFMA16(qa[s][0], kf[jt][0], a);
        a = MFMA16(qa[s][1], kf[jt][1], a);
#pragma unroll
        for (int r = 0; r < 4; r++)
          S_lds[(s * 16 + quad * 4 + r) * 776 + (jt * 16 + l16) * 24 + w] = f2bf(a[r]);
      }
    // ---- prefetch next K ----
    if (n + 1 < niter) {
      const int j0n = j0 + 32;
#pragma unroll
      for (int jt = 0; jt < 2; jt++) {
        int jr = min(j0n + jt * 16 + l16, 2063);
        const unsigned short* kp = Kb + (size_t)jr * 64 + quad * 8;
        kf[jt][0] = *(const short8*)kp;
        kf[jt][1] = *(const short8*)(kp + 32);
      }
    }
    BARLDS();
    // ---- pre-mix + exp/l -> P (in place, wave-private columns) ----
#pragma unroll
    for (int u = 0; u < 4; u++) {
      const int iloc = u >> 1, jt = u & 1, ii = w * 2 + iloc;
      const int sc = ii * 776 + (jt * 16 + l16) * 24;
      const short8 bb = *(const short8*)(S_lds + sc + hoff);
      floatx4 sp = (floatx4){0.f, 0.f, 0.f, 0.f};
      sp = MFMA16(preA, bb, sp);
      const int jg = j0 + jt * 16 + l16;
      const bool keep = jg <= (i0 + ii + 16);
#pragma unroll
      for (int r = 0; r < 4; r++)
        S_lds[sc + quad * 4 + r] = f2bf(keep ? __expf(sp[r]) * rl[iloc][r] : 0.f);
    }
    LGKM0();  // own-wave P writes visible before re-read
    // ---- post-mix -> Pp (AV A-frag layout) ----
#pragma unroll
    for (int u = 0; u < 4; u++) {
      const int iloc = u >> 1, jt = u & 1, ii = w * 2 + iloc;
      const int sc = ii * 776 + (jt * 16 + l16) * 24;
      const short8 pf = *(const short8*)(S_lds + sc + hoff);
      floatx4 pp = (floatx4){0.f, 0.f, 0.f, 0.f};
      pp = MFMA16(postA, pf, pp);
#pragma unroll
      for (int r = 0; r < 4; r++)
        Pp_lds[(quad * 4 + r) * 1288 + ii * 40 + jt * 16 + l16] = f2bf(pp[r]);
    }
    BARLDS();
    // ---- AV: wave w = value head k2=w, K = 32 j's ----
#pragma unroll
    for (int g = 0; g < 2; g++) {
      const short8 paf = *(const short8*)(Pp_lds + w * 1288 + (g * 16 + l16) * 40 + quad * 8);
#pragma unroll
      for (int d = 0; d < 4; d++) oacc[g][d] = MFMA16(paf, vf[d], oacc[g][d]);
    }
  }
  // ---- accumulate into O_ws fp32 ----
#pragma unroll
  for (int g = 0; g < 2; g++)
#pragma unroll
    for (int d = 0; d < 4; d++)
#pragma unroll
      for (int r = 0; r < 4; r++)
        atomicAdd(O_ws + (size_t)(b * 2048 + i0 + g * 16 + quad * 4 + r) * 1024 +
                      w * 64 + d * 16 + l16,
                  oacc[g][d][r]);
}

// ---------------------------------------------------------------------------
extern "C" void kernel_launch(void* const* d_in, const int* in_sizes, int n_in,
                              void* d_out, int out_size, void* d_ws, size_t ws_size,
                              hipStream_t stream) {
  (void)in_sizes; (void)n_in; (void)out_size; (void)ws_size;
  const float* x     = (const float*)d_in[0];
  const float* Wq    = (const float*)d_in[1];
  const float* Wkv   = (const float*)d_in[2];
  const float* Wo    = (const float*)d_in[3];
  const float* pre   = (const float*)d_in[4];
  const float* post  = (const float*)d_in[5];
  const float* mem_k = (const float*)d_in[6];
  const float* mem_v = (const float*)d_in[7];
  float* out = (float*)d_out;
  char* ws = (char*)d_ws;

  // Temporally-aliased workspace (total 67,239,936 B):
  //   [0, 16.8M):  xb(8M)+WbT(6M)+pad — dead after qkv gemm -> O_ws fp32 16M
  //   [16.8M, 41.9M): qkv bf16 — dead after attn_av -> WoT (2M)
  //   [41.9M, 50.4M): Kw ; [50.4M, 58.9M): Vt
  //   [58.9M, 67.2M): l_ws (256K, dead after attn_av) then attn_b bf16 (8M)
  unsigned short* xb     = (unsigned short*)(ws);
  unsigned short* WbT    = (unsigned short*)(ws + 8388608);
  float*          O_ws   = (float*)(ws);                     // 16,777,216 B
  unsigned short* qkv    = (unsigned short*)(ws + 16777216); // 25,165,824 B
  unsigned short* WoT    = (unsigned short*)(ws + 16777216); // 2 MB (post-attn)
  unsigned short* Kw     = (unsigned short*)(ws + 41943040); //  8,454,144 B
  unsigned short* Vt     = (unsigned short*)(ws + 50397184); //  8,454,144 B
  float*          l_ws   = (float*)(ws + 58851328);          //    262,144 B
  unsigned short* attn_b = (unsigned short*)(ws + 58851328); //  8,388,608 B

  conv_bf16<<<2048, 256, 0, stream>>>(x, xb, 524288);
  transW<<<dim3(32, 32), 256, 0, stream>>>(Wq, 1024, WbT, 0);
  transW<<<dim3(64, 32), 256, 0, stream>>>(Wkv, 2048, WbT, 1024);
  gemm_bt<<<dim3(32, 24), 256, 0, stream>>>(xb, WbT, qkv, nullptr, 4096, 3072, 1024, 0);
  fill_K<<<2064, 256, 0, stream>>>(qkv, mem_k, Kw);
  fill_Vt<<<dim3(129, 16, 2), 256, 0, stream>>>(qkv, mem_v, Vt);
  hipMemsetAsync(O_ws, 0, 16777216, stream);   // xb/WbT dead now
  hipMemsetAsync(l_ws, 0, 262144, stream);
  attn_stats<<<dim3(13, 64, 2), 1024, 0, stream>>>(qkv, Kw, pre, l_ws);
  attn_av<<<dim3(13, 64, 2), 1024, 0, stream>>>(qkv, Kw, Vt, pre, post, l_ws, O_ws);
  conv_bf16<<<2048, 256, 0, stream>>>(O_ws, attn_b, 524288);  // l_ws dead now
  transW<<<dim3(32, 32), 256, 0, stream>>>(Wo, 1024, WoT, 0); // qkv dead now
  gemm_bt<<<dim3(32, 8), 256, 0, stream>>>(attn_b, WoT, nullptr, out, 4096, 1024, 1024, 1);
}